// Round 4
// baseline (427.274 us; speedup 1.0000x reference)
//
#include <hip/hip_runtime.h>
#include <stdint.h>

// ---------------------------------------------------------------------------
// LinearBlockSparseAttention on MI355X (gfx950) — round 2 kernel (2nd resubmit;
// R2/R3 never ran: GPU acquisition timeouts)
//   Wqp = Wqkv_q @ proj, Wkp = Wqkv_k @ proj   (fp32 on device, bf16 out)
//   [qf|kf|v] = epi( x @ [Wqp|Wkp|Wv] )        (256^2 8-phase MFMA GEMM, N=5120)
//       epi: cols<4096 -> elu(x)+1, else identity
//   per (b,h,m): S = qf@kf^T (K=128), out = (S@v) / (rowsum(S)+eps)  [in-place over v]
//   y = out @ Wout + bout                      (256^2 8-phase GEMM, N=1024)
// d_out doubles as scratch for xb/BtAll (dead before final GEMM writes).
// ---------------------------------------------------------------------------

typedef unsigned short u16;
typedef __attribute__((ext_vector_type(4))) float f32x4;
typedef __attribute__((ext_vector_type(8))) __bf16 bf16x8;
typedef __attribute__((ext_vector_type(8))) u16 us8;
typedef __attribute__((ext_vector_type(4))) u16 us4;

#define GLOAD_LDS16(g, l)                                                      \
  __builtin_amdgcn_global_load_lds(                                            \
      (const __attribute__((address_space(1))) void*)(g),                      \
      (__attribute__((address_space(3))) void*)(l), 16, 0, 0)

__device__ __forceinline__ u16 f2bf(float f) {
  union { float f; unsigned u; } x; x.f = f;
  return (u16)((x.u + 0x7fffu + ((x.u >> 16) & 1u)) >> 16);
}

__device__ __forceinline__ bf16x8 ld8(const void* p) {
  return __builtin_bit_cast(bf16x8, *(const us8*)p);
}

__device__ __forceinline__ f32x4 mfma16(bf16x8 a, bf16x8 b, f32x4 c) {
  return __builtin_amdgcn_mfma_f32_16x16x32_bf16(a, b, c, 0, 0, 0);
}

// ---------------------------------------------------------------------------
// elementwise fp32 -> bf16 cast
__global__ void cast_bf16_k(const float* __restrict__ in, u16* __restrict__ out,
                            int n4) {
  int stride = gridDim.x * blockDim.x;
  for (int i = blockIdx.x * blockDim.x + threadIdx.x; i < n4; i += stride) {
    f32x4 v = ((const f32x4*)in)[i];
    us4 o;
    o[0] = f2bf(v[0]); o[1] = f2bf(v[1]); o[2] = f2bf(v[2]); o[3] = f2bf(v[3]);
    ((us4*)out)[i] = o;
  }
}

// transpose + cast: in [R][C] f32 -> out [C][R] bf16
__global__ __launch_bounds__(256)
void tcast_k(const float* __restrict__ in, u16* __restrict__ out, int R, int C) {
  __shared__ float tile[32][33];
  int tx = threadIdx.x & 31, ty = threadIdx.x >> 5;
  int r0 = blockIdx.y * 32, c0 = blockIdx.x * 32;
#pragma unroll
  for (int i = 0; i < 32; i += 8)
    tile[ty + i][tx] = in[(size_t)(r0 + ty + i) * C + c0 + tx];
  __syncthreads();
#pragma unroll
  for (int i = 0; i < 32; i += 8)
    out[(size_t)(c0 + ty + i) * R + r0 + tx] = f2bf(tile[tx][ty + i]);
}

// WvT: dst[j][e] = Wqkv[e][2048+j]  (1024 x 1024)
__global__ __launch_bounds__(256)
void tcastv_k(const float* __restrict__ Wqkv, u16* __restrict__ dst) {
  __shared__ float tile[32][33];
  int tx = threadIdx.x & 31, ty = threadIdx.x >> 5;
  int e0 = blockIdx.y * 32, j0 = blockIdx.x * 32;
#pragma unroll
  for (int i = 0; i < 32; i += 8)
    tile[ty + i][tx] = Wqkv[(size_t)(e0 + ty + i) * 3072 + 2048 + j0 + tx];
  __syncthreads();
#pragma unroll
  for (int i = 0; i < 32; i += 8)
    dst[(size_t)(j0 + ty + i) * 1024 + e0 + tx] = f2bf(tile[tx][ty + i]);
}

// Wqp/Wkp builder: BtAll[n=qk*2048+h*128+f][e] =
//   sum_d Wqkv[e][qk*1024+h*64+d] * proj[h][d][f]   (fp32, bf16 out)
__global__ __launch_bounds__(256)
void wqpb_k(const float* __restrict__ Wqkv, const float* __restrict__ proj,
            u16* __restrict__ BtAll) {
  __shared__ float pl[64][128];  // proj[h], 32 KB
  const int ec = blockIdx.x, h = blockIdx.y, qk = blockIdx.z;
  const float* ph = proj + (size_t)h * 8192;
  for (int i = threadIdx.x; i < 2048; i += 256)
    ((f32x4*)&pl[0][0])[i] = ((const f32x4*)ph)[i];
  __syncthreads();
  const int e = ec * 128 + (threadIdx.x >> 1);
  const int f0 = (threadIdx.x & 1) * 64;
  float wrow[64];
  const float* src = Wqkv + (size_t)e * 3072 + qk * 1024 + h * 64;
#pragma unroll
  for (int i = 0; i < 16; ++i)
    *(f32x4*)&wrow[i * 4] = *(const f32x4*)&src[i * 4];
  u16* dst = BtAll + (size_t)(qk * 2048 + h * 128) * 1024 + e;
  for (int fg = 0; fg < 16; ++fg) {
    f32x4 acc = (f32x4){0.f, 0.f, 0.f, 0.f};
    const int f = f0 + fg * 4;
#pragma unroll
    for (int d = 0; d < 64; ++d) {
      f32x4 p = *(f32x4*)&pl[d][f];
      acc += wrow[d] * p;
    }
#pragma unroll
    for (int u = 0; u < 4; ++u) dst[(size_t)(f + u) * 1024] = f2bf(acc[u]);
  }
}

// ---------------------------------------------------------------------------
// 256x256 8-phase GEMM, BK=64, 8 waves (2M x 4N), 128 KB LDS double-buffer,
// XOR-swizzled LDS (granule ^= row&7) via pre-swizzled global source,
// counted vmcnt(4) once per K-tile, setprio around MFMA clusters.
// C[M,N] = A[M,K(lda)] @ Bt[N,K(ldb)]^T
// EPI 0: cols<4096 -> elu+1 -> o_qkf[.,4096]; cols>=4096 -> o_v[.,1024] (bf16)
// EPI 1: o_f32[.,1024] = x + bias[col]
template <int EPI>
__global__ __launch_bounds__(512, 1)
void gemm8p_k(const u16* __restrict__ A, int lda,
              const u16* __restrict__ Bt, int ldb,
              const float* __restrict__ bias,
              u16* __restrict__ o_qkf, u16* __restrict__ o_v,
              float* __restrict__ o_f32, int K, int ntx) {
  __shared__ __align__(16) char lds[131072];
  const int tid = threadIdx.x, lane = tid & 63, w = tid >> 6;
  const int wm = w >> 2, wn = w & 3;
  const int lr = lane & 15, lg = lane >> 4;
  // bijective XCD swizzle (gridDim.x % 8 == 0)
  const int cpx = (int)gridDim.x >> 3;
  const int bid = blockIdx.x;
  const int s = (bid & 7) * cpx + (bid >> 3);
  const int bxN = (s % ntx) * 256;
  const int byM = (s / ntx) * 256;
  const int nt = K >> 6;

  // staging geometry: thread covers row = j*64 + w*8 + (lane>>3),
  // source col pre-swizzled so linear gload_lds dest yields granule^=(row&7)
  const int srow = w * 8 + (lane >> 3);
  const int scol = ((lane & 7) ^ ((lane >> 3) & 7)) * 8;

  auto stg = [&](const u16* src, int ld, int row0, int kt, int dstoff) {
#pragma unroll
    for (int j = 0; j < 2; ++j)
      GLOAD_LDS16(src + (size_t)(row0 + j * 64 + srow) * ld + kt + scol,
                  lds + dstoff + j * 8192 + w * 1024);
  };
  auto stgA0 = [&](int t) { stg(A, lda, byM, t * 64, (t & 1) * 65536); };
  auto stgA1 = [&](int t) { stg(A, lda, byM + 128, t * 64, (t & 1) * 65536 + 16384); };
  auto stgB0 = [&](int t) { stg(Bt, ldb, bxN, t * 64, (t & 1) * 65536 + 32768); };
  auto stgB1 = [&](int t) { stg(Bt, ldb, bxN + 128, t * 64, (t & 1) * 65536 + 49152); };

  f32x4 acc[8][4];
#pragma unroll
  for (int i = 0; i < 8; ++i)
#pragma unroll
    for (int j = 0; j < 4; ++j) acc[i][j] = (f32x4){0.f, 0.f, 0.f, 0.f};

  // prologue: tile0 (4 halves) + tile1 B halves; counted wait leaves tile1's
  // B halves (4 loads) in flight.
  stgA0(0); stgA1(0); stgB0(0); stgB1(0);
  if (nt > 1) {
    stgB0(1); stgB1(1);
    asm volatile("s_waitcnt vmcnt(4)" ::: "memory");
  } else {
    asm volatile("s_waitcnt vmcnt(0)" ::: "memory");
  }
  __builtin_amdgcn_s_barrier();

  for (int t = 0; t < nt; ++t) {
    const char* Ab = lds + (t & 1) * 65536 + wm * 16384;
    const char* Bb = lds + (t & 1) * 65536 + 32768 + (wn >> 1) * 16384;
    const int brow = (wn & 1) * 64;
    bf16x8 a2[4][2], b2[4][2];

    // ---- phase 1: quadrant (mi 0-3, nj 0-1); stage A-half0(t+1)
#pragma unroll
    for (int i = 0; i < 4; ++i)
#pragma unroll
      for (int ks = 0; ks < 2; ++ks) {
        int row = i * 16 + lr;
        a2[i][ks] = ld8(Ab + row * 128 + ((ks * 64 + lg * 16) ^ ((row & 7) << 4)));
      }
#pragma unroll
    for (int j = 0; j < 2; ++j)
#pragma unroll
      for (int ks = 0; ks < 2; ++ks) {
        int row = brow + j * 16 + lr;
        b2[j][ks] = ld8(Bb + row * 128 + ((ks * 64 + lg * 16) ^ ((row & 7) << 4)));
      }
    if (t + 1 < nt) stgA0(t + 1);
    __builtin_amdgcn_s_barrier();
    asm volatile("s_waitcnt lgkmcnt(0)" ::: "memory");
    __builtin_amdgcn_sched_barrier(0);
    __builtin_amdgcn_s_setprio(1);
#pragma unroll
    for (int i = 0; i < 4; ++i)
#pragma unroll
      for (int j = 0; j < 2; ++j)
#pragma unroll
        for (int ks = 0; ks < 2; ++ks)
          acc[i][j] = mfma16(a2[i][ks], b2[j][ks], acc[i][j]);
    __builtin_amdgcn_s_setprio(0);
    __builtin_amdgcn_s_barrier();

    // ---- phase 2: (mi 0-3, nj 2-3); stage A-half1(t+1)
#pragma unroll
    for (int j = 2; j < 4; ++j)
#pragma unroll
      for (int ks = 0; ks < 2; ++ks) {
        int row = brow + j * 16 + lr;
        b2[j][ks] = ld8(Bb + row * 128 + ((ks * 64 + lg * 16) ^ ((row & 7) << 4)));
      }
    if (t + 1 < nt) stgA1(t + 1);
    __builtin_amdgcn_s_barrier();
    asm volatile("s_waitcnt lgkmcnt(0)" ::: "memory");
    __builtin_amdgcn_sched_barrier(0);
    __builtin_amdgcn_s_setprio(1);
#pragma unroll
    for (int i = 0; i < 4; ++i)
#pragma unroll
      for (int j = 2; j < 4; ++j)
#pragma unroll
        for (int ks = 0; ks < 2; ++ks)
          acc[i][j] = mfma16(a2[i][ks], b2[j][ks], acc[i][j]);
    __builtin_amdgcn_s_setprio(0);
    __builtin_amdgcn_s_barrier();

    // ---- phase 3: (mi 4-7, nj 0-1); stage B-half0(t+2)
    //      (B-half0 of current dbuf last read in phases 1-2 -> safe)
#pragma unroll
    for (int i = 0; i < 4; ++i)
#pragma unroll
      for (int ks = 0; ks < 2; ++ks) {
        int row = (4 + i) * 16 + lr;
        a2[i][ks] = ld8(Ab + row * 128 + ((ks * 64 + lg * 16) ^ ((row & 7) << 4)));
      }
    if (t + 2 < nt) stgB0(t + 2);
    __builtin_amdgcn_s_barrier();
    asm volatile("s_waitcnt lgkmcnt(0)" ::: "memory");
    __builtin_amdgcn_sched_barrier(0);
    __builtin_amdgcn_s_setprio(1);
#pragma unroll
    for (int i = 0; i < 4; ++i)
#pragma unroll
      for (int j = 0; j < 2; ++j)
#pragma unroll
        for (int ks = 0; ks < 2; ++ks)
          acc[4 + i][j] = mfma16(a2[i][ks], b2[j][ks], acc[4 + i][j]);
    __builtin_amdgcn_s_setprio(0);
    __builtin_amdgcn_s_barrier();

    // ---- phase 4: (mi 4-7, nj 2-3); stage B-half1(t+2); counted vmcnt
    if (t + 2 < nt) stgB1(t + 2);
    if (t < nt - 2)
      asm volatile("s_waitcnt vmcnt(4)" ::: "memory");
    else
      asm volatile("s_waitcnt vmcnt(0)" ::: "memory");
    __builtin_amdgcn_s_barrier();
    __builtin_amdgcn_s_setprio(1);
#pragma unroll
    for (int i = 0; i < 4; ++i)
#pragma unroll
      for (int j = 2; j < 4; ++j)
#pragma unroll
        for (int ks = 0; ks < 2; ++ks)
          acc[4 + i][j] = mfma16(a2[i][ks], b2[j][ks], acc[4 + i][j]);
    __builtin_amdgcn_s_setprio(0);
    __builtin_amdgcn_s_barrier();
  }

  // epilogue
  const bool doelu = (EPI == 0) && (bxN < 4096);
#pragma unroll
  for (int mi = 0; mi < 8; ++mi)
#pragma unroll
    for (int nj = 0; nj < 4; ++nj) {
      const int col = bxN + wn * 64 + nj * 16 + lr;
#pragma unroll
      for (int rr = 0; rr < 4; ++rr) {
        const int row = byM + wm * 128 + mi * 16 + lg * 4 + rr;
        float x = acc[mi][nj][rr];
        if (EPI == 0) {
          if (doelu) {
            float v = x > 0.f ? x + 1.f : __expf(x);  // elu(x)+1
            o_qkf[(size_t)row * 4096 + col] = f2bf(v);
          } else {
            o_v[(size_t)row * 1024 + (col - 4096)] = f2bf(x);
          }
        } else {
          o_f32[(size_t)row * 1024 + col] = x + bias[col];
        }
      }
    }
}

// ---------------------------------------------------------------------------
// Light fused block attention: S = qf@kf^T (global frags), rowsum, PV.
// Writes output in-place over its own v cells (exclusive per block).
__global__ __launch_bounds__(64)
void attn_lite_k(const u16* __restrict__ qkf, u16* __restrict__ vbuf) {
  __shared__ __align__(16) u16 V_l[32 * 72];
  __shared__ __align__(16) u16 S_l[32 * 32];
  const int lane = threadIdx.x;
  const int bid = blockIdx.x;
  const int m = bid & 127, h = (bid >> 7) & 15, b = bid >> 11;
  const size_t t0 = (size_t)b * 4096 + (size_t)m * 32;
  const u16* qf = qkf + t0 * 4096 + h * 128;
  const u16* kf = qf + 2048;
  u16* vv = vbuf + t0 * 1024 + h * 64;
  const int lr = lane & 15, lg = lane >> 4;

  // stage V rows (16B per lane, coalesced-ish)
#pragma unroll
  for (int it = 0; it < 4; ++it) {
    int s2 = it * 8 + (lane >> 3);
    int d0 = (lane & 7) * 8;
    *(us8*)&V_l[s2 * 72 + d0] = *(const us8*)&vv[(size_t)s2 * 1024 + d0];
  }

  // S = qf @ kf^T  (32x32, K=128), frags straight from global
  f32x4 sacc[2][2];
#pragma unroll
  for (int mm = 0; mm < 2; ++mm)
#pragma unroll
    for (int nn = 0; nn < 2; ++nn) sacc[mm][nn] = (f32x4){0.f, 0.f, 0.f, 0.f};
#pragma unroll
  for (int ks = 0; ks < 4; ++ks) {
    bf16x8 aq[2], bk[2];
#pragma unroll
    for (int mm = 0; mm < 2; ++mm) {
      aq[mm] = ld8(&qf[(size_t)(mm * 16 + lr) * 4096 + ks * 32 + lg * 8]);
      bk[mm] = ld8(&kf[(size_t)(mm * 16 + lr) * 4096 + ks * 32 + lg * 8]);
    }
#pragma unroll
    for (int mm = 0; mm < 2; ++mm)
#pragma unroll
      for (int nn = 0; nn < 2; ++nn)
        sacc[mm][nn] = mfma16(aq[mm], bk[nn], sacc[mm][nn]);
  }

  // row sums (z denominator): reduce over 16-lane column group
  float rs[2][4];
#pragma unroll
  for (int mm = 0; mm < 2; ++mm)
#pragma unroll
    for (int r = 0; r < 4; ++r) {
      float t = sacc[mm][0][r] + sacc[mm][1][r];
      t += __shfl_xor(t, 1);
      t += __shfl_xor(t, 2);
      t += __shfl_xor(t, 4);
      t += __shfl_xor(t, 8);
      rs[mm][r] = t;
    }

  // S -> bf16 LDS (swizzled, 64 B rows)
#pragma unroll
  for (int mm = 0; mm < 2; ++mm)
#pragma unroll
    for (int nn = 0; nn < 2; ++nn)
#pragma unroll
      for (int r = 0; r < 4; ++r) {
        int row = mm * 16 + lg * 4 + r;
        int byi = (nn * 16 + lr) * 2;
        *(u16*)((char*)S_l + row * 64 + (byi ^ ((row & 3) << 4))) =
            f2bf(sacc[mm][nn][r]);
      }

  // PV: out = S @ V  (32x64, K=32)
  bf16x8 vfr[4];
#pragma unroll
  for (int nn = 0; nn < 4; ++nn) {
    us8 g;
#pragma unroll
    for (int j = 0; j < 8; ++j) g[j] = V_l[(lg * 8 + j) * 72 + nn * 16 + lr];
    vfr[nn] = __builtin_bit_cast(bf16x8, g);
  }
  f32x4 pacc[2][4];
#pragma unroll
  for (int mm = 0; mm < 2; ++mm)
#pragma unroll
    for (int nn = 0; nn < 4; ++nn) pacc[mm][nn] = (f32x4){0.f, 0.f, 0.f, 0.f};
#pragma unroll
  for (int mm = 0; mm < 2; ++mm) {
    int row = mm * 16 + lr;
    int byi = lg * 16;
    bf16x8 a = ld8((char*)S_l + row * 64 + (byi ^ ((row & 3) << 4)));
#pragma unroll
    for (int nn = 0; nn < 4; ++nn) pacc[mm][nn] = mfma16(a, vfr[nn], pacc[mm][nn]);
  }

  // normalize + write in-place over v
#pragma unroll
  for (int mm = 0; mm < 2; ++mm)
#pragma unroll
    for (int r = 0; r < 4; ++r) {
      float z = 1.f / (rs[mm][r] + 1e-8f);
      int q = mm * 16 + lg * 4 + r;
#pragma unroll
      for (int nn = 0; nn < 4; ++nn)
        vv[(size_t)q * 1024 + nn * 16 + lr] = f2bf(pacc[mm][nn][r] * z);
    }
}

// ---------------------------------------------------------------------------
extern "C" void kernel_launch(void* const* d_in, const int* in_sizes, int n_in,
                              void* d_out, int out_size, void* d_ws,
                              size_t ws_size, hipStream_t stream) {
  const float* x = (const float*)d_in[0];     // [4,4096,1024]
  const float* Wqkv = (const float*)d_in[1];  // [1024,3072]
  const float* proj = (const float*)d_in[2];  // [16,64,128]
  const float* Wout = (const float*)d_in[3];  // [1024,1024]
  const float* bout = (const float*)d_in[4];  // [1024]
  float* out = (float*)d_out;                 // [4,4096,1024] fp32

  char* ws = (char*)d_ws;
  char* doc = (char*)d_out;  // d_out as scratch: dead before final GEMM writes

  u16* xb    = (u16*)doc;                   // 33,554,432 B  (x in bf16)
  u16* btall = (u16*)(doc + 33554432);      // 10,485,760 B  [Wqp|Wkp|Wv]^T [5120][1024]
  u16* qkf   = (u16*)ws;                    // 134,217,728 B [16384][4096] qf|kf
  u16* vbuf  = (u16*)(ws + 134217728);      // 33,554,432 B  [16384][1024] v -> attn out
  u16* woutT = (u16*)(ws + 167772160);      // 2,097,152 B   (ws total 169.9 MB)

  cast_bf16_k<<<2048, 256, 0, stream>>>(x, xb, 4194304);
  tcastv_k<<<dim3(32, 32), 256, 0, stream>>>(Wqkv, btall + (size_t)4096 * 1024);
  wqpb_k<<<dim3(8, 16, 2), 256, 0, stream>>>(Wqkv, proj, btall);
  tcast_k<<<dim3(32, 32), 256, 0, stream>>>(Wout, woutT, 1024, 1024);

  gemm8p_k<0><<<1280, 512, 0, stream>>>(xb, 1024, btall, 1024, nullptr,
                                        qkf, vbuf, nullptr, 1024, 20);

  attn_lite_k<<<8192, 64, 0, stream>>>(qkf, vbuf);

  gemm8p_k<1><<<256, 512, 0, stream>>>(vbuf, 1024, woutT, 1024, bout,
                                       nullptr, nullptr, out, 1024, 4);
}

// Round 5
// 418.275 us; speedup vs baseline: 1.0215x; 1.0215x over previous
//
#include <hip/hip_runtime.h>
#include <stdint.h>

// ---------------------------------------------------------------------------
// LinearBlockSparseAttention on MI355X (gfx950) — round 5
// R5 change (only gemm8p_k K-loop): remove lgkmcnt(0)/sched_barrier(0) pins
// that serialized LDS-reads vs MFMA (R4: 6400 cyc/tile = fully serial).
// New: 2 regions/tile, reads+stage+MFMA in one scheduling region, compiler
// emits counted lgkmcnt -> ds_read drains under MFMA. 1 raw barrier/region,
// counted vmcnt(4) at tile end.
// ---------------------------------------------------------------------------

typedef unsigned short u16;
typedef __attribute__((ext_vector_type(4))) float f32x4;
typedef __attribute__((ext_vector_type(8))) __bf16 bf16x8;
typedef __attribute__((ext_vector_type(8))) u16 us8;
typedef __attribute__((ext_vector_type(4))) u16 us4;

#define GLOAD_LDS16(g, l)                                                      \
  __builtin_amdgcn_global_load_lds(                                            \
      (const __attribute__((address_space(1))) void*)(g),                      \
      (__attribute__((address_space(3))) void*)(l), 16, 0, 0)

__device__ __forceinline__ u16 f2bf(float f) {
  union { float f; unsigned u; } x; x.f = f;
  return (u16)((x.u + 0x7fffu + ((x.u >> 16) & 1u)) >> 16);
}

__device__ __forceinline__ bf16x8 ld8(const void* p) {
  return __builtin_bit_cast(bf16x8, *(const us8*)p);
}

__device__ __forceinline__ f32x4 mfma16(bf16x8 a, bf16x8 b, f32x4 c) {
  return __builtin_amdgcn_mfma_f32_16x16x32_bf16(a, b, c, 0, 0, 0);
}

// ---------------------------------------------------------------------------
// elementwise fp32 -> bf16 cast
__global__ void cast_bf16_k(const float* __restrict__ in, u16* __restrict__ out,
                            int n4) {
  int stride = gridDim.x * blockDim.x;
  for (int i = blockIdx.x * blockDim.x + threadIdx.x; i < n4; i += stride) {
    f32x4 v = ((const f32x4*)in)[i];
    us4 o;
    o[0] = f2bf(v[0]); o[1] = f2bf(v[1]); o[2] = f2bf(v[2]); o[3] = f2bf(v[3]);
    ((us4*)out)[i] = o;
  }
}

// transpose + cast: in [R][C] f32 -> out [C][R] bf16
__global__ __launch_bounds__(256)
void tcast_k(const float* __restrict__ in, u16* __restrict__ out, int R, int C) {
  __shared__ float tile[32][33];
  int tx = threadIdx.x & 31, ty = threadIdx.x >> 5;
  int r0 = blockIdx.y * 32, c0 = blockIdx.x * 32;
#pragma unroll
  for (int i = 0; i < 32; i += 8)
    tile[ty + i][tx] = in[(size_t)(r0 + ty + i) * C + c0 + tx];
  __syncthreads();
#pragma unroll
  for (int i = 0; i < 32; i += 8)
    out[(size_t)(c0 + ty + i) * R + r0 + tx] = f2bf(tile[tx][ty + i]);
}

// WvT: dst[j][e] = Wqkv[e][2048+j]  (1024 x 1024)
__global__ __launch_bounds__(256)
void tcastv_k(const float* __restrict__ Wqkv, u16* __restrict__ dst) {
  __shared__ float tile[32][33];
  int tx = threadIdx.x & 31, ty = threadIdx.x >> 5;
  int e0 = blockIdx.y * 32, j0 = blockIdx.x * 32;
#pragma unroll
  for (int i = 0; i < 32; i += 8)
    tile[ty + i][tx] = Wqkv[(size_t)(e0 + ty + i) * 3072 + 2048 + j0 + tx];
  __syncthreads();
#pragma unroll
  for (int i = 0; i < 32; i += 8)
    dst[(size_t)(j0 + ty + i) * 1024 + e0 + tx] = f2bf(tile[tx][ty + i]);
}

// Wqp/Wkp builder: BtAll[n=qk*2048+h*128+f][e] =
//   sum_d Wqkv[e][qk*1024+h*64+d] * proj[h][d][f]   (fp32, bf16 out)
__global__ __launch_bounds__(256)
void wqpb_k(const float* __restrict__ Wqkv, const float* __restrict__ proj,
            u16* __restrict__ BtAll) {
  __shared__ float pl[64][128];  // proj[h], 32 KB
  const int ec = blockIdx.x, h = blockIdx.y, qk = blockIdx.z;
  const float* ph = proj + (size_t)h * 8192;
  for (int i = threadIdx.x; i < 2048; i += 256)
    ((f32x4*)&pl[0][0])[i] = ((const f32x4*)ph)[i];
  __syncthreads();
  const int e = ec * 128 + (threadIdx.x >> 1);
  const int f0 = (threadIdx.x & 1) * 64;
  float wrow[64];
  const float* src = Wqkv + (size_t)e * 3072 + qk * 1024 + h * 64;
#pragma unroll
  for (int i = 0; i < 16; ++i)
    *(f32x4*)&wrow[i * 4] = *(const f32x4*)&src[i * 4];
  u16* dst = BtAll + (size_t)(qk * 2048 + h * 128) * 1024 + e;
  for (int fg = 0; fg < 16; ++fg) {
    f32x4 acc = (f32x4){0.f, 0.f, 0.f, 0.f};
    const int f = f0 + fg * 4;
#pragma unroll
    for (int d = 0; d < 64; ++d) {
      f32x4 p = *(f32x4*)&pl[d][f];
      acc += wrow[d] * p;
    }
#pragma unroll
    for (int u = 0; u < 4; ++u) dst[(size_t)(f + u) * 1024] = f2bf(acc[u]);
  }
}

// ---------------------------------------------------------------------------
// 256x256 GEMM, BK=64, 8 waves (2M x 4N), 128 KB LDS double-buffer,
// XOR-swizzled LDS (granule ^= row&7) via pre-swizzled global source.
// 2 scheduling regions per K-tile (compiler-interleaved ds_read||MFMA),
// 1 raw s_barrier per region, counted vmcnt(4) once per K-tile.
// C[M,N] = A[M,K(lda)] @ Bt[N,K(ldb)]^T
// EPI 0: cols<4096 -> elu+1 -> o_qkf[.,4096]; cols>=4096 -> o_v[.,1024] (bf16)
// EPI 1: o_f32[.,1024] = x + bias[col]
template <int EPI>
__global__ __launch_bounds__(512, 1)
void gemm8p_k(const u16* __restrict__ A, int lda,
              const u16* __restrict__ Bt, int ldb,
              const float* __restrict__ bias,
              u16* __restrict__ o_qkf, u16* __restrict__ o_v,
              float* __restrict__ o_f32, int K, int ntx) {
  __shared__ __align__(16) char lds[131072];
  const int tid = threadIdx.x, lane = tid & 63, w = tid >> 6;
  const int wm = w >> 2, wn = w & 3;
  const int lr = lane & 15, lg = lane >> 4;
  // bijective XCD swizzle (gridDim.x % 8 == 0)
  const int cpx = (int)gridDim.x >> 3;
  const int bid = blockIdx.x;
  const int s = (bid & 7) * cpx + (bid >> 3);
  const int bxN = (s % ntx) * 256;
  const int byM = (s / ntx) * 256;
  const int nt = K >> 6;

  // staging geometry: thread covers row = j*64 + w*8 + (lane>>3),
  // source col pre-swizzled so linear gload_lds dest yields granule^=(row&7)
  const int srow = w * 8 + (lane >> 3);
  const int scol = ((lane & 7) ^ ((lane >> 3) & 7)) * 8;

  auto stg = [&](const u16* src, int ld, int row0, int kt, int dstoff) {
#pragma unroll
    for (int j = 0; j < 2; ++j)
      GLOAD_LDS16(src + (size_t)(row0 + j * 64 + srow) * ld + kt + scol,
                  lds + dstoff + j * 8192 + w * 1024);
  };
  auto stgA0 = [&](int t) { stg(A, lda, byM, t * 64, (t & 1) * 65536); };
  auto stgA1 = [&](int t) { stg(A, lda, byM + 128, t * 64, (t & 1) * 65536 + 16384); };
  auto stgB0 = [&](int t) { stg(Bt, ldb, bxN, t * 64, (t & 1) * 65536 + 32768); };
  auto stgB1 = [&](int t) { stg(Bt, ldb, bxN + 128, t * 64, (t & 1) * 65536 + 49152); };

  f32x4 acc[8][4];
#pragma unroll
  for (int i = 0; i < 8; ++i)
#pragma unroll
    for (int j = 0; j < 4; ++j) acc[i][j] = (f32x4){0.f, 0.f, 0.f, 0.f};

  // prologue: tile0 (4 halves) + tile1 B halves; counted wait leaves tile1's
  // B halves (4 loads) in flight.
  stgA0(0); stgA1(0); stgB0(0); stgB1(0);
  if (nt > 1) {
    stgB0(1); stgB1(1);
    asm volatile("s_waitcnt vmcnt(4)" ::: "memory");
  } else {
    asm volatile("s_waitcnt vmcnt(0)" ::: "memory");
  }
  __builtin_amdgcn_s_barrier();

  for (int t = 0; t < nt; ++t) {
    const char* Ab = lds + (t & 1) * 65536 + wm * 16384;
    const char* Bb = lds + (t & 1) * 65536 + 32768 + (wn >> 1) * 16384;
    const int brow = (wn & 1) * 64;
    bf16x8 alo[4][2], ahi[4][2], bl[4][2];

    // ---- region A: Q1+Q2 (mi 0-3, all nj); stage A halves of t+1.
    // reads + staging + MFMAs in one region: compiler emits counted lgkmcnt,
    // so MFMA(i) starts when its own frags land; later reads drain under MFMA.
    if (t + 1 < nt) { stgA0(t + 1); stgA1(t + 1); }
#pragma unroll
    for (int i = 0; i < 4; ++i)
#pragma unroll
      for (int ks = 0; ks < 2; ++ks) {
        int row = i * 16 + lr;
        alo[i][ks] = ld8(Ab + row * 128 + ((ks * 64 + lg * 16) ^ ((row & 7) << 4)));
      }
#pragma unroll
    for (int j = 0; j < 4; ++j)
#pragma unroll
      for (int ks = 0; ks < 2; ++ks) {
        int row = brow + j * 16 + lr;
        bl[j][ks] = ld8(Bb + row * 128 + ((ks * 64 + lg * 16) ^ ((row & 7) << 4)));
      }
#pragma unroll
    for (int i = 0; i < 4; ++i)
#pragma unroll
      for (int j = 0; j < 4; ++j)
#pragma unroll
        for (int ks = 0; ks < 2; ++ks)
          acc[i][j] = mfma16(alo[i][ks], bl[j][ks], acc[i][j]);
    // barrier 1: all region-A reads consumed above -> B-half of this dbuf may
    // be overwritten by stgB(t+2) after this point.
    __builtin_amdgcn_s_barrier();

    // ---- region B: Q3+Q4 (mi 4-7, all nj; B-frags reused from regs);
    // stage B halves of t+2; counted vmcnt at tile end.
    if (t + 2 < nt) { stgB0(t + 2); stgB1(t + 2); }
#pragma unroll
    for (int i = 0; i < 4; ++i)
#pragma unroll
      for (int ks = 0; ks < 2; ++ks) {
        int row = (4 + i) * 16 + lr;
        ahi[i][ks] = ld8(Ab + row * 128 + ((ks * 64 + lg * 16) ^ ((row & 7) << 4)));
      }
#pragma unroll
    for (int i = 0; i < 4; ++i)
#pragma unroll
      for (int j = 0; j < 4; ++j)
#pragma unroll
        for (int ks = 0; ks < 2; ++ks)
          acc[4 + i][j] = mfma16(ahi[i][ks], bl[j][ks], acc[4 + i][j]);
    // tile-end: A(t+1)+B(t+1) must be resident for next tile's reads.
    // queue: [B(t+1) 4, A(t+1) 4, B(t+2) 4] -> vmcnt(4) retires thru A(t+1).
    if (t < nt - 2)
      asm volatile("s_waitcnt vmcnt(4)" ::: "memory");
    else
      asm volatile("s_waitcnt vmcnt(0)" ::: "memory");
    __builtin_amdgcn_s_barrier();
  }

  // epilogue
  const bool doelu = (EPI == 0) && (bxN < 4096);
#pragma unroll
  for (int mi = 0; mi < 8; ++mi)
#pragma unroll
    for (int nj = 0; nj < 4; ++nj) {
      const int col = bxN + wn * 64 + nj * 16 + lr;
#pragma unroll
      for (int rr = 0; rr < 4; ++rr) {
        const int row = byM + wm * 128 + mi * 16 + lg * 4 + rr;
        float x = acc[mi][nj][rr];
        if (EPI == 0) {
          if (doelu) {
            float v = x > 0.f ? x + 1.f : __expf(x);  // elu(x)+1
            o_qkf[(size_t)row * 4096 + col] = f2bf(v);
          } else {
            o_v[(size_t)row * 1024 + (col - 4096)] = f2bf(x);
          }
        } else {
          o_f32[(size_t)row * 1024 + col] = x + bias[col];
        }
      }
    }
}

// ---------------------------------------------------------------------------
// Light fused block attention: S = qf@kf^T (global frags), rowsum, PV.
// Writes output in-place over its own v cells (exclusive per block).
__global__ __launch_bounds__(64)
void attn_lite_k(const u16* __restrict__ qkf, u16* __restrict__ vbuf) {
  __shared__ __align__(16) u16 V_l[32 * 72];
  __shared__ __align__(16) u16 S_l[32 * 32];
  const int lane = threadIdx.x;
  const int bid = blockIdx.x;
  const int m = bid & 127, h = (bid >> 7) & 15, b = bid >> 11;
  const size_t t0 = (size_t)b * 4096 + (size_t)m * 32;
  const u16* qf = qkf + t0 * 4096 + h * 128;
  const u16* kf = qf + 2048;
  u16* vv = vbuf + t0 * 1024 + h * 64;
  const int lr = lane & 15, lg = lane >> 4;

  // stage V rows (16B per lane)
#pragma unroll
  for (int it = 0; it < 4; ++it) {
    int s2 = it * 8 + (lane >> 3);
    int d0 = (lane & 7) * 8;
    *(us8*)&V_l[s2 * 72 + d0] = *(const us8*)&vv[(size_t)s2 * 1024 + d0];
  }

  // S = qf @ kf^T  (32x32, K=128), frags straight from global
  f32x4 sacc[2][2];
#pragma unroll
  for (int mm = 0; mm < 2; ++mm)
#pragma unroll
    for (int nn = 0; nn < 2; ++nn) sacc[mm][nn] = (f32x4){0.f, 0.f, 0.f, 0.f};
#pragma unroll
  for (int ks = 0; ks < 4; ++ks) {
    bf16x8 aq[2], bk[2];
#pragma unroll
    for (int mm = 0; mm < 2; ++mm) {
      aq[mm] = ld8(&qf[(size_t)(mm * 16 + lr) * 4096 + ks * 32 + lg * 8]);
      bk[mm] = ld8(&kf[(size_t)(mm * 16 + lr) * 4096 + ks * 32 + lg * 8]);
    }
#pragma unroll
    for (int mm = 0; mm < 2; ++mm)
#pragma unroll
      for (int nn = 0; nn < 2; ++nn)
        sacc[mm][nn] = mfma16(aq[mm], bk[nn], sacc[mm][nn]);
  }

  // row sums (z denominator): reduce over 16-lane column group
  float rs[2][4];
#pragma unroll
  for (int mm = 0; mm < 2; ++mm)
#pragma unroll
    for (int r = 0; r < 4; ++r) {
      float t = sacc[mm][0][r] + sacc[mm][1][r];
      t += __shfl_xor(t, 1);
      t += __shfl_xor(t, 2);
      t += __shfl_xor(t, 4);
      t += __shfl_xor(t, 8);
      rs[mm][r] = t;
    }

  // S -> bf16 LDS (swizzled, 64 B rows)
#pragma unroll
  for (int mm = 0; mm < 2; ++mm)
#pragma unroll
    for (int nn = 0; nn < 2; ++nn)
#pragma unroll
      for (int r = 0; r < 4; ++r) {
        int row = mm * 16 + lg * 4 + r;
        int byi = (nn * 16 + lr) * 2;
        *(u16*)((char*)S_l + row * 64 + (byi ^ ((row & 3) << 4))) =
            f2bf(sacc[mm][nn][r]);
      }

  // PV: out = S @ V  (32x64, K=32)
  bf16x8 vfr[4];
#pragma unroll
  for (int nn = 0; nn < 4; ++nn) {
    us8 g;
#pragma unroll
    for (int j = 0; j < 8; ++j) g[j] = V_l[(lg * 8 + j) * 72 + nn * 16 + lr];
    vfr[nn] = __builtin_bit_cast(bf16x8, g);
  }
  f32x4 pacc[2][4];
#pragma unroll
  for (int mm = 0; mm < 2; ++mm)
#pragma unroll
    for (int nn = 0; nn < 4; ++nn) pacc[mm][nn] = (f32x4){0.f, 0.f, 0.f, 0.f};
#pragma unroll
  for (int mm = 0; mm < 2; ++mm) {
    int row = mm * 16 + lr;
    int byi = lg * 16;
    bf16x8 a = ld8((char*)S_l + row * 64 + (byi ^ ((row & 3) << 4)));
#pragma unroll
    for (int nn = 0; nn < 4; ++nn) pacc[mm][nn] = mfma16(a, vfr[nn], pacc[mm][nn]);
  }

  // normalize + write in-place over v
#pragma unroll
  for (int mm = 0; mm < 2; ++mm)
#pragma unroll
    for (int r = 0; r < 4; ++r) {
      float z = 1.f / (rs[mm][r] + 1e-8f);
      int q = mm * 16 + lg * 4 + r;
#pragma unroll
      for (int nn = 0; nn < 4; ++nn)
        vv[(size_t)q * 1024 + nn * 16 + lr] = f2bf(pacc[mm][nn][r] * z);
    }
}

// ---------------------------------------------------------------------------
extern "C" void kernel_launch(void* const* d_in, const int* in_sizes, int n_in,
                              void* d_out, int out_size, void* d_ws,
                              size_t ws_size, hipStream_t stream) {
  const float* x = (const float*)d_in[0];     // [4,4096,1024]
  const float* Wqkv = (const float*)d_in[1];  // [1024,3072]
  const float* proj = (const float*)d_in[2];  // [16,64,128]
  const float* Wout = (const float*)d_in[3];  // [1024,1024]
  const float* bout = (const float*)d_in[4];  // [1024]
  float* out = (float*)d_out;                 // [4,4096,1024] fp32

  char* ws = (char*)d_ws;
  char* doc = (char*)d_out;  // d_out as scratch: dead before final GEMM writes

  u16* xb    = (u16*)doc;                   // 33,554,432 B  (x in bf16)
  u16* btall = (u16*)(doc + 33554432);      // 10,485,760 B  [Wqp|Wkp|Wv]^T [5120][1024]
  u16* qkf   = (u16*)ws;                    // 134,217,728 B [16384][4096] qf|kf
  u16* vbuf  = (u16*)(ws + 134217728);      // 33,554,432 B  [16384][1024] v -> attn out
  u16* woutT = (u16*)(ws + 167772160);      // 2,097,152 B   (ws total 169.9 MB)

  cast_bf16_k<<<2048, 256, 0, stream>>>(x, xb, 4194304);
  tcastv_k<<<dim3(32, 32), 256, 0, stream>>>(Wqkv, btall + (size_t)4096 * 1024);
  wqpb_k<<<dim3(8, 16, 2), 256, 0, stream>>>(Wqkv, proj, btall);
  tcast_k<<<dim3(32, 32), 256, 0, stream>>>(Wout, woutT, 1024, 1024);

  gemm8p_k<0><<<1280, 512, 0, stream>>>(xb, 1024, btall, 1024, nullptr,
                                        qkf, vbuf, nullptr, 1024, 20);

  attn_lite_k<<<8192, 64, 0, stream>>>(qkf, vbuf);

  gemm8p_k<1><<<256, 512, 0, stream>>>(vbuf, 1024, woutT, 1024, bout,
                                       nullptr, nullptr, out, 1024, 4);
}

// Round 6
// 414.616 us; speedup vs baseline: 1.0305x; 1.0088x over previous
//
#include <hip/hip_runtime.h>
#include <stdint.h>

// ---------------------------------------------------------------------------
// LinearBlockSparseAttention on MI355X (gfx950) — round 6
// R6 vs R5: (1) EPI0 epilogue LDS-bounce -> coalesced 16B/lane stores (R5 had
// 32B runs -> RFO; FETCH 229MB vs 43MB inputs). (2) qf/kf emitted block-tiled
// qkfB[mblk][h][qk][32][128] so attn frag reads are full-line from global.
// K-loop unchanged from R5 (2 regions/tile, counted vmcnt(4)).
// ---------------------------------------------------------------------------

typedef unsigned short u16;
typedef __attribute__((ext_vector_type(4))) float f32x4;
typedef __attribute__((ext_vector_type(8))) __bf16 bf16x8;
typedef __attribute__((ext_vector_type(8))) u16 us8;
typedef __attribute__((ext_vector_type(4))) u16 us4;

#define GLOAD_LDS16(g, l)                                                      \
  __builtin_amdgcn_global_load_lds(                                            \
      (const __attribute__((address_space(1))) void*)(g),                      \
      (__attribute__((address_space(3))) void*)(l), 16, 0, 0)

__device__ __forceinline__ u16 f2bf(float f) {
  union { float f; unsigned u; } x; x.f = f;
  return (u16)((x.u + 0x7fffu + ((x.u >> 16) & 1u)) >> 16);
}

__device__ __forceinline__ bf16x8 ld8(const void* p) {
  return __builtin_bit_cast(bf16x8, *(const us8*)p);
}

__device__ __forceinline__ f32x4 mfma16(bf16x8 a, bf16x8 b, f32x4 c) {
  return __builtin_amdgcn_mfma_f32_16x16x32_bf16(a, b, c, 0, 0, 0);
}

// ---------------------------------------------------------------------------
__global__ void cast_bf16_k(const float* __restrict__ in, u16* __restrict__ out,
                            int n4) {
  int stride = gridDim.x * blockDim.x;
  for (int i = blockIdx.x * blockDim.x + threadIdx.x; i < n4; i += stride) {
    f32x4 v = ((const f32x4*)in)[i];
    us4 o;
    o[0] = f2bf(v[0]); o[1] = f2bf(v[1]); o[2] = f2bf(v[2]); o[3] = f2bf(v[3]);
    ((us4*)out)[i] = o;
  }
}

// transpose + cast: in [R][C] f32 -> out [C][R] bf16
__global__ __launch_bounds__(256)
void tcast_k(const float* __restrict__ in, u16* __restrict__ out, int R, int C) {
  __shared__ float tile[32][33];
  int tx = threadIdx.x & 31, ty = threadIdx.x >> 5;
  int r0 = blockIdx.y * 32, c0 = blockIdx.x * 32;
#pragma unroll
  for (int i = 0; i < 32; i += 8)
    tile[ty + i][tx] = in[(size_t)(r0 + ty + i) * C + c0 + tx];
  __syncthreads();
#pragma unroll
  for (int i = 0; i < 32; i += 8)
    out[(size_t)(c0 + ty + i) * R + r0 + tx] = f2bf(tile[tx][ty + i]);
}

// WvT: dst[j][e] = Wqkv[e][2048+j]  (1024 x 1024)
__global__ __launch_bounds__(256)
void tcastv_k(const float* __restrict__ Wqkv, u16* __restrict__ dst) {
  __shared__ float tile[32][33];
  int tx = threadIdx.x & 31, ty = threadIdx.x >> 5;
  int e0 = blockIdx.y * 32, j0 = blockIdx.x * 32;
#pragma unroll
  for (int i = 0; i < 32; i += 8)
    tile[ty + i][tx] = Wqkv[(size_t)(e0 + ty + i) * 3072 + 2048 + j0 + tx];
  __syncthreads();
#pragma unroll
  for (int i = 0; i < 32; i += 8)
    dst[(size_t)(j0 + ty + i) * 1024 + e0 + tx] = f2bf(tile[tx][ty + i]);
}

// Wqp/Wkp builder: BtAll[n=qk*2048+h*128+f][e] = sum_d Wqkv[e][qk*1024+h*64+d]*proj[h][d][f]
__global__ __launch_bounds__(256)
void wqpb_k(const float* __restrict__ Wqkv, const float* __restrict__ proj,
            u16* __restrict__ BtAll) {
  __shared__ float pl[64][128];
  const int ec = blockIdx.x, h = blockIdx.y, qk = blockIdx.z;
  const float* ph = proj + (size_t)h * 8192;
  for (int i = threadIdx.x; i < 2048; i += 256)
    ((f32x4*)&pl[0][0])[i] = ((const f32x4*)ph)[i];
  __syncthreads();
  const int e = ec * 128 + (threadIdx.x >> 1);
  const int f0 = (threadIdx.x & 1) * 64;
  float wrow[64];
  const float* src = Wqkv + (size_t)e * 3072 + qk * 1024 + h * 64;
#pragma unroll
  for (int i = 0; i < 16; ++i)
    *(f32x4*)&wrow[i * 4] = *(const f32x4*)&src[i * 4];
  u16* dst = BtAll + (size_t)(qk * 2048 + h * 128) * 1024 + e;
  for (int fg = 0; fg < 16; ++fg) {
    f32x4 acc = (f32x4){0.f, 0.f, 0.f, 0.f};
    const int f = f0 + fg * 4;
#pragma unroll
    for (int d = 0; d < 64; ++d) {
      f32x4 p = *(f32x4*)&pl[d][f];
      acc += wrow[d] * p;
    }
#pragma unroll
    for (int u = 0; u < 4; ++u) dst[(size_t)(f + u) * 1024] = f2bf(acc[u]);
  }
}

// ---------------------------------------------------------------------------
// 256x256 GEMM, BK=64, 8 waves (2Mx4N), 128KB LDS dbuf, XOR-swizzled LDS via
// pre-swizzled global source, 2 regions/K-tile, counted vmcnt(4) per tile.
// EPI 0: cols<4096 -> elu+1 -> block-tiled qkfB[mblk][h][qk][32][128] (bf16)
//        cols>=4096 -> v -> o_v[token][1024] (bf16)   [both via LDS bounce]
// EPI 1: o_f32[token][1024] = x + bias[col]            [direct 64B stores]
template <int EPI>
__global__ __launch_bounds__(512, 1)
void gemm8p_k(const u16* __restrict__ A, int lda,
              const u16* __restrict__ Bt, int ldb,
              const float* __restrict__ bias,
              u16* __restrict__ o_qkf, u16* __restrict__ o_v,
              float* __restrict__ o_f32, int K, int ntx) {
  __shared__ __align__(16) char lds[131072];
  const int tid = threadIdx.x, lane = tid & 63, w = tid >> 6;
  const int wm = w >> 2, wn = w & 3;
  const int lr = lane & 15, lg = lane >> 4;
  const int cpx = (int)gridDim.x >> 3;
  const int bid = blockIdx.x;
  const int s = (bid & 7) * cpx + (bid >> 3);
  const int bxN = (s % ntx) * 256;
  const int byM = (s / ntx) * 256;
  const int nt = K >> 6;

  const int srow = w * 8 + (lane >> 3);
  const int scol = ((lane & 7) ^ ((lane >> 3) & 7)) * 8;

  auto stg = [&](const u16* src, int ld, int row0, int kt, int dstoff) {
#pragma unroll
    for (int j = 0; j < 2; ++j)
      GLOAD_LDS16(src + (size_t)(row0 + j * 64 + srow) * ld + kt + scol,
                  lds + dstoff + j * 8192 + w * 1024);
  };
  auto stgA0 = [&](int t) { stg(A, lda, byM, t * 64, (t & 1) * 65536); };
  auto stgA1 = [&](int t) { stg(A, lda, byM + 128, t * 64, (t & 1) * 65536 + 16384); };
  auto stgB0 = [&](int t) { stg(Bt, ldb, bxN, t * 64, (t & 1) * 65536 + 32768); };
  auto stgB1 = [&](int t) { stg(Bt, ldb, bxN + 128, t * 64, (t & 1) * 65536 + 49152); };

  f32x4 acc[8][4];
#pragma unroll
  for (int i = 0; i < 8; ++i)
#pragma unroll
    for (int j = 0; j < 4; ++j) acc[i][j] = (f32x4){0.f, 0.f, 0.f, 0.f};

  stgA0(0); stgA1(0); stgB0(0); stgB1(0);
  if (nt > 1) {
    stgB0(1); stgB1(1);
    asm volatile("s_waitcnt vmcnt(4)" ::: "memory");
  } else {
    asm volatile("s_waitcnt vmcnt(0)" ::: "memory");
  }
  __builtin_amdgcn_s_barrier();

  for (int t = 0; t < nt; ++t) {
    const char* Ab = lds + (t & 1) * 65536 + wm * 16384;
    const char* Bb = lds + (t & 1) * 65536 + 32768 + (wn >> 1) * 16384;
    const int brow = (wn & 1) * 64;
    bf16x8 alo[4][2], ahi[4][2], bl[4][2];

    // region A: mi 0-3 x all nj; stage A halves of t+1 (other dbuf, safe).
    if (t + 1 < nt) { stgA0(t + 1); stgA1(t + 1); }
#pragma unroll
    for (int i = 0; i < 4; ++i)
#pragma unroll
      for (int ks = 0; ks < 2; ++ks) {
        int row = i * 16 + lr;
        alo[i][ks] = ld8(Ab + row * 128 + ((ks * 64 + lg * 16) ^ ((row & 7) << 4)));
      }
#pragma unroll
    for (int j = 0; j < 4; ++j)
#pragma unroll
      for (int ks = 0; ks < 2; ++ks) {
        int row = brow + j * 16 + lr;
        bl[j][ks] = ld8(Bb + row * 128 + ((ks * 64 + lg * 16) ^ ((row & 7) << 4)));
      }
#pragma unroll
    for (int i = 0; i < 4; ++i)
#pragma unroll
      for (int j = 0; j < 4; ++j)
#pragma unroll
        for (int ks = 0; ks < 2; ++ks)
          acc[i][j] = mfma16(alo[i][ks], bl[j][ks], acc[i][j]);
    __builtin_amdgcn_s_barrier();  // region-A reads consumed; B-half reusable

    // region B: mi 4-7 (B frags reused from regs); stage B halves of t+2.
    if (t + 2 < nt) { stgB0(t + 2); stgB1(t + 2); }
#pragma unroll
    for (int i = 0; i < 4; ++i)
#pragma unroll
      for (int ks = 0; ks < 2; ++ks) {
        int row = (4 + i) * 16 + lr;
        ahi[i][ks] = ld8(Ab + row * 128 + ((ks * 64 + lg * 16) ^ ((row & 7) << 4)));
      }
#pragma unroll
    for (int i = 0; i < 4; ++i)
#pragma unroll
      for (int j = 0; j < 4; ++j)
#pragma unroll
        for (int ks = 0; ks < 2; ++ks)
          acc[4 + i][j] = mfma16(ahi[i][ks], bl[j][ks], acc[4 + i][j]);
    // queue: [B(t+1)4, A(t+1)4, B(t+2)4]; vmcnt(4) retires thru A(t+1).
    if (t < nt - 2)
      asm volatile("s_waitcnt vmcnt(4)" ::: "memory");
    else
      asm volatile("s_waitcnt vmcnt(0)" ::: "memory");
    __builtin_amdgcn_s_barrier();
  }

  // ---- epilogue -----------------------------------------------------------
  if (EPI == 1) {
    // direct stores: 16 lanes x 4B = 64B aligned runs (full lines, no RFO)
#pragma unroll
    for (int mi = 0; mi < 8; ++mi)
#pragma unroll
      for (int nj = 0; nj < 4; ++nj) {
        const int col = bxN + wn * 64 + nj * 16 + lr;
        const float bia = bias[col];
#pragma unroll
        for (int rr = 0; rr < 4; ++rr) {
          const int row = byM + wm * 128 + mi * 16 + lg * 4 + rr;
          o_f32[(size_t)row * 1024 + col] = acc[mi][nj][rr] + bia;
        }
      }
    return;
  }

  // EPI 0: bounce through LDS (staging buffers dead after final barrier).
  const bool doelu = (bxN < 4096);
  u16* cl = (u16*)lds;  // [256][256] bf16 tile, rows XOR-swizzled by (row&7)<<4
#pragma unroll
  for (int mi = 0; mi < 8; ++mi)
#pragma unroll
    for (int nj = 0; nj < 4; ++nj)
#pragma unroll
      for (int rr = 0; rr < 4; ++rr) {
        const int rl = wm * 128 + mi * 16 + lg * 4 + rr;
        const int clm = wn * 64 + nj * 16 + lr;
        float xv = acc[mi][nj][rr];
        float v = doelu ? (xv > 0.f ? xv + 1.f : __expf(xv)) : xv;
        *(u16*)((char*)cl + ((rl * 512 + clm * 2) ^ ((rl & 7) << 4))) = f2bf(v);
      }
  __syncthreads();
  if (doelu) {
    // qf/kf -> block-tiled qkfB[mblk][h][qk][32][128]
#pragma unroll
    for (int it = 0; it < 16; ++it) {
      const int chunk = it * 512 + tid;
      const int r = chunk >> 5, g = (chunk >> 4) & 1, k8 = chunk & 15;
      us8 val = *(us8*)((char*)cl + ((r * 512 + g * 256 + k8 * 16) ^ ((r & 7) << 4)));
      const int token = byM + r;
      const int cg = bxN + g * 128;
      const int qk = cg >> 11;           // 0: q-region (<2048), 1: k-region
      const int h = (cg >> 7) & 15;
      const size_t dst =
          ((((size_t)(token >> 5) * 16 + h) * 2 + qk) * 32 + (token & 31)) * 128 +
          k8 * 8;
      *(us8*)&o_qkf[dst] = val;
    }
  } else {
    // v -> o_v[token][1024] (row-major)
#pragma unroll
    for (int it = 0; it < 16; ++it) {
      const int chunk = it * 512 + tid;
      const int r = chunk >> 5, k = chunk & 31;
      us8 val = *(us8*)((char*)cl + ((r * 512 + k * 16) ^ ((r & 7) << 4)));
      *(us8*)&o_v[(size_t)(byM + r) * 1024 + (bxN - 4096) + k * 8] = val;
    }
  }
}

// ---------------------------------------------------------------------------
// Block attention: qf/kf frags straight from block-tiled qkfB (full-line reads),
// S = qf@kf^T, rowsum z, PV from LDS-staged V; writes in-place over v.
__global__ __launch_bounds__(64)
void attn_lite_k(const u16* __restrict__ qkfB, u16* __restrict__ vbuf) {
  __shared__ __align__(16) u16 V_l[32 * 72];
  __shared__ __align__(16) u16 S_l[32 * 32];
  const int lane = threadIdx.x;
  const int bid = blockIdx.x;
  const int h = bid & 15, mglob = bid >> 4;
  const u16* qf = qkfB + (size_t)mglob * 131072 + h * 8192;  // [32][128]
  const u16* kf = qf + 4096;
  u16* vv = vbuf + (size_t)mglob * 32 * 1024 + h * 64;
  const int lr = lane & 15, lg = lane >> 4;

  // stage V rows (16B per lane)
#pragma unroll
  for (int it = 0; it < 4; ++it) {
    int s2 = it * 8 + (lane >> 3);
    int d0 = (lane & 7) * 8;
    *(us8*)&V_l[s2 * 72 + d0] = *(const us8*)&vv[(size_t)s2 * 1024 + d0];
  }

  // S = qf @ kf^T  (32x32, K=128)
  f32x4 sacc[2][2];
#pragma unroll
  for (int mm = 0; mm < 2; ++mm)
#pragma unroll
    for (int nn = 0; nn < 2; ++nn) sacc[mm][nn] = (f32x4){0.f, 0.f, 0.f, 0.f};
#pragma unroll
  for (int ks = 0; ks < 4; ++ks) {
    bf16x8 aq[2], bk[2];
#pragma unroll
    for (int mm = 0; mm < 2; ++mm) {
      aq[mm] = ld8(&qf[(mm * 16 + lr) * 128 + ks * 32 + lg * 8]);
      bk[mm] = ld8(&kf[(mm * 16 + lr) * 128 + ks * 32 + lg * 8]);
    }
#pragma unroll
    for (int mm = 0; mm < 2; ++mm)
#pragma unroll
      for (int nn = 0; nn < 2; ++nn)
        sacc[mm][nn] = mfma16(aq[mm], bk[nn], sacc[mm][nn]);
  }

  // row sums (z denominator)
  float rs[2][4];
#pragma unroll
  for (int mm = 0; mm < 2; ++mm)
#pragma unroll
    for (int r = 0; r < 4; ++r) {
      float t = sacc[mm][0][r] + sacc[mm][1][r];
      t += __shfl_xor(t, 1);
      t += __shfl_xor(t, 2);
      t += __shfl_xor(t, 4);
      t += __shfl_xor(t, 8);
      rs[mm][r] = t;
    }

  // S -> bf16 LDS (swizzled)
#pragma unroll
  for (int mm = 0; mm < 2; ++mm)
#pragma unroll
    for (int nn = 0; nn < 2; ++nn)
#pragma unroll
      for (int r = 0; r < 4; ++r) {
        int row = mm * 16 + lg * 4 + r;
        int byi = (nn * 16 + lr) * 2;
        *(u16*)((char*)S_l + row * 64 + (byi ^ ((row & 3) << 4))) =
            f2bf(sacc[mm][nn][r]);
      }

  // PV: out = S @ V (32x64, K=32)
  bf16x8 vfr[4];
#pragma unroll
  for (int nn = 0; nn < 4; ++nn) {
    us8 g;
#pragma unroll
    for (int j = 0; j < 8; ++j) g[j] = V_l[(lg * 8 + j) * 72 + nn * 16 + lr];
    vfr[nn] = __builtin_bit_cast(bf16x8, g);
  }
  f32x4 pacc[2][4];
#pragma unroll
  for (int mm = 0; mm < 2; ++mm)
#pragma unroll
    for (int nn = 0; nn < 4; ++nn) pacc[mm][nn] = (f32x4){0.f, 0.f, 0.f, 0.f};
#pragma unroll
  for (int mm = 0; mm < 2; ++mm) {
    int row = mm * 16 + lr;
    int byi = lg * 16;
    bf16x8 a = ld8((char*)S_l + row * 64 + (byi ^ ((row & 3) << 4)));
#pragma unroll
    for (int nn = 0; nn < 4; ++nn) pacc[mm][nn] = mfma16(a, vfr[nn], pacc[mm][nn]);
  }

  // normalize + write in-place over v
#pragma unroll
  for (int mm = 0; mm < 2; ++mm)
#pragma unroll
    for (int r = 0; r < 4; ++r) {
      float z = 1.f / (rs[mm][r] + 1e-8f);
      int q = mm * 16 + lg * 4 + r;
#pragma unroll
      for (int nn = 0; nn < 4; ++nn)
        vv[(size_t)q * 1024 + nn * 16 + lr] = f2bf(pacc[mm][nn][r] * z);
    }
}

// ---------------------------------------------------------------------------
extern "C" void kernel_launch(void* const* d_in, const int* in_sizes, int n_in,
                              void* d_out, int out_size, void* d_ws,
                              size_t ws_size, hipStream_t stream) {
  const float* x = (const float*)d_in[0];     // [4,4096,1024]
  const float* Wqkv = (const float*)d_in[1];  // [1024,3072]
  const float* proj = (const float*)d_in[2];  // [16,64,128]
  const float* Wout = (const float*)d_in[3];  // [1024,1024]
  const float* bout = (const float*)d_in[4];  // [1024]
  float* out = (float*)d_out;                 // [4,4096,1024] fp32

  char* ws = (char*)d_ws;
  char* doc = (char*)d_out;  // d_out as scratch: dead before final GEMM writes

  u16* xb    = (u16*)doc;                   // 33,554,432 B  (x in bf16)
  u16* btall = (u16*)(doc + 33554432);      // 10,485,760 B  [Wqp|Wkp|Wv]^T [5120][1024]
  u16* qkfB  = (u16*)ws;                    // 134,217,728 B block-tiled qf|kf
  u16* vbuf  = (u16*)(ws + 134217728);      // 33,554,432 B  v -> attn out
  u16* woutT = (u16*)(ws + 167772160);      // 2,097,152 B

  cast_bf16_k<<<2048, 256, 0, stream>>>(x, xb, 4194304);
  tcastv_k<<<dim3(32, 32), 256, 0, stream>>>(Wqkv, btall + (size_t)4096 * 1024);
  wqpb_k<<<dim3(8, 16, 2), 256, 0, stream>>>(Wqkv, proj, btall);
  tcast_k<<<dim3(32, 32), 256, 0, stream>>>(Wout, woutT, 1024, 1024);

  gemm8p_k<0><<<1280, 512, 0, stream>>>(xb, 1024, btall, 1024, nullptr,
                                        qkfB, vbuf, nullptr, 1024, 20);

  attn_lite_k<<<8192, 64, 0, stream>>>(qkfB, vbuf);

  gemm8p_k<1><<<256, 512, 0, stream>>>(vbuf, 1024, woutT, 1024, bout,
                                       nullptr, nullptr, out, 1024, 4);
}

// Round 7
// 394.654 us; speedup vs baseline: 1.0827x; 1.0506x over previous
//
#include <hip/hip_runtime.h>
#include <stdint.h>

// ---------------------------------------------------------------------------
// LinearBlockSparseAttention on MI355X (gfx950) — round 7
// R7 vs R6: attention fused into the qkf-GEMM epilogue. BtAll columns are
// head-major ([h][qf128|kf128]) so each 256-col GEMM tile = one head, and the
// epilogue LDS bounce tile holds qf|kf for 8 attn blocks (one per wave).
// v computed by a prior small GEMM (EPI2). Deletes attn_lite + 268 MB HBM.
// K-loop unchanged from R5/R6 (2 regions/tile, counted vmcnt(4)).
// ---------------------------------------------------------------------------

typedef unsigned short u16;
typedef __attribute__((ext_vector_type(4))) float f32x4;
typedef __attribute__((ext_vector_type(8))) __bf16 bf16x8;
typedef __attribute__((ext_vector_type(8))) u16 us8;
typedef __attribute__((ext_vector_type(4))) u16 us4;

#define GLOAD_LDS16(g, l)                                                      \
  __builtin_amdgcn_global_load_lds(                                            \
      (const __attribute__((address_space(1))) void*)(g),                      \
      (__attribute__((address_space(3))) void*)(l), 16, 0, 0)

__device__ __forceinline__ u16 f2bf(float f) {
  union { float f; unsigned u; } x; x.f = f;
  return (u16)((x.u + 0x7fffu + ((x.u >> 16) & 1u)) >> 16);
}

__device__ __forceinline__ bf16x8 ld8(const void* p) {
  return __builtin_bit_cast(bf16x8, *(const us8*)p);
}

__device__ __forceinline__ f32x4 mfma16(bf16x8 a, bf16x8 b, f32x4 c) {
  return __builtin_amdgcn_mfma_f32_16x16x32_bf16(a, b, c, 0, 0, 0);
}

// ---------------------------------------------------------------------------
__global__ void cast_bf16_k(const float* __restrict__ in, u16* __restrict__ out,
                            int n4) {
  int stride = gridDim.x * blockDim.x;
  for (int i = blockIdx.x * blockDim.x + threadIdx.x; i < n4; i += stride) {
    f32x4 v = ((const f32x4*)in)[i];
    us4 o;
    o[0] = f2bf(v[0]); o[1] = f2bf(v[1]); o[2] = f2bf(v[2]); o[3] = f2bf(v[3]);
    ((us4*)out)[i] = o;
  }
}

// transpose + cast: in [R][C] f32 -> out [C][R] bf16
__global__ __launch_bounds__(256)
void tcast_k(const float* __restrict__ in, u16* __restrict__ out, int R, int C) {
  __shared__ float tile[32][33];
  int tx = threadIdx.x & 31, ty = threadIdx.x >> 5;
  int r0 = blockIdx.y * 32, c0 = blockIdx.x * 32;
#pragma unroll
  for (int i = 0; i < 32; i += 8)
    tile[ty + i][tx] = in[(size_t)(r0 + ty + i) * C + c0 + tx];
  __syncthreads();
#pragma unroll
  for (int i = 0; i < 32; i += 8)
    out[(size_t)(c0 + ty + i) * R + r0 + tx] = f2bf(tile[tx][ty + i]);
}

// WvT: dst[j][e] = Wqkv[e][2048+j]  (1024 x 1024)
__global__ __launch_bounds__(256)
void tcastv_k(const float* __restrict__ Wqkv, u16* __restrict__ dst) {
  __shared__ float tile[32][33];
  int tx = threadIdx.x & 31, ty = threadIdx.x >> 5;
  int e0 = blockIdx.y * 32, j0 = blockIdx.x * 32;
#pragma unroll
  for (int i = 0; i < 32; i += 8)
    tile[ty + i][tx] = Wqkv[(size_t)(e0 + ty + i) * 3072 + 2048 + j0 + tx];
  __syncthreads();
#pragma unroll
  for (int i = 0; i < 32; i += 8)
    dst[(size_t)(j0 + ty + i) * 1024 + e0 + tx] = f2bf(tile[tx][ty + i]);
}

// Wqp/Wkp builder, head-major rows: Bt[n = h*256 + qk*128 + f][e] =
//   sum_d Wqkv[e][qk*1024+h*64+d] * proj[h][d][f]
__global__ __launch_bounds__(256)
void wqpb_k(const float* __restrict__ Wqkv, const float* __restrict__ proj,
            u16* __restrict__ Bt) {
  __shared__ float pl[64][128];
  const int ec = blockIdx.x, h = blockIdx.y, qk = blockIdx.z;
  const float* ph = proj + (size_t)h * 8192;
  for (int i = threadIdx.x; i < 2048; i += 256)
    ((f32x4*)&pl[0][0])[i] = ((const f32x4*)ph)[i];
  __syncthreads();
  const int e = ec * 128 + (threadIdx.x >> 1);
  const int f0 = (threadIdx.x & 1) * 64;
  float wrow[64];
  const float* src = Wqkv + (size_t)e * 3072 + qk * 1024 + h * 64;
#pragma unroll
  for (int i = 0; i < 16; ++i)
    *(f32x4*)&wrow[i * 4] = *(const f32x4*)&src[i * 4];
  u16* dst = Bt + (size_t)(h * 256 + qk * 128) * 1024 + e;
  for (int fg = 0; fg < 16; ++fg) {
    f32x4 acc = (f32x4){0.f, 0.f, 0.f, 0.f};
    const int f = f0 + fg * 4;
#pragma unroll
    for (int d = 0; d < 64; ++d) {
      f32x4 p = *(f32x4*)&pl[d][f];
      acc += wrow[d] * p;
    }
#pragma unroll
    for (int u = 0; u < 4; ++u) dst[(size_t)(f + u) * 1024] = f2bf(acc[u]);
  }
}

// ---------------------------------------------------------------------------
// 256x256 GEMM, BK=64, 8 waves (2Mx4N), 128KB LDS dbuf, XOR-swizzled LDS via
// pre-swizzled global source, 2 regions/K-tile, counted vmcnt(4) per tile.
// EPI 0: head-tile: elu+1 -> LDS bounce -> fused block attention -> o_bf16
//        (in-place over v_in cells), using v_in tile loaded early to regs.
// EPI 1: o_f32[token][1024] = x + bias[col]  (direct 64B stores)
// EPI 2: o_bf16[token][1024] = x (bf16, via LDS bounce, row-major)
template <int EPI>
__global__ __launch_bounds__(512, 1)
void gemm8p_k(const u16* __restrict__ A, int lda,
              const u16* __restrict__ Bt, int ldb,
              const float* __restrict__ bias,
              u16* __restrict__ o_bf16, const u16* __restrict__ v_in,
              float* __restrict__ o_f32, int K, int ntx) {
  __shared__ __align__(16) char lds[131072];
  const int tid = threadIdx.x, lane = tid & 63, w = tid >> 6;
  const int wm = w >> 2, wn = w & 3;
  const int lr = lane & 15, lg = lane >> 4;
  const int cpx = (int)gridDim.x >> 3;
  const int bid = blockIdx.x;
  const int s = (bid & 7) * cpx + (bid >> 3);
  const int bxN = (s % ntx) * 256;
  const int byM = (s / ntx) * 256;
  const int nt = K >> 6;

  const int srow = w * 8 + (lane >> 3);
  const int scol = ((lane & 7) ^ ((lane >> 3) & 7)) * 8;

  auto stg = [&](const u16* src, int ld, int row0, int kt, int dstoff) {
#pragma unroll
    for (int j = 0; j < 2; ++j)
      GLOAD_LDS16(src + (size_t)(row0 + j * 64 + srow) * ld + kt + scol,
                  lds + dstoff + j * 8192 + w * 1024);
  };
  auto stgA0 = [&](int t) { stg(A, lda, byM, t * 64, (t & 1) * 65536); };
  auto stgA1 = [&](int t) { stg(A, lda, byM + 128, t * 64, (t & 1) * 65536 + 16384); };
  auto stgB0 = [&](int t) { stg(Bt, ldb, bxN, t * 64, (t & 1) * 65536 + 32768); };
  auto stgB1 = [&](int t) { stg(Bt, ldb, bxN + 128, t * 64, (t & 1) * 65536 + 49152); };

  f32x4 acc[8][4];
#pragma unroll
  for (int i = 0; i < 8; ++i)
#pragma unroll
    for (int j = 0; j < 4; ++j) acc[i][j] = (f32x4){0.f, 0.f, 0.f, 0.f};

  stgA0(0); stgA1(0); stgB0(0); stgB1(0);
  if (nt > 1) {
    stgB0(1); stgB1(1);
    asm volatile("s_waitcnt vmcnt(4)" ::: "memory");
  } else {
    asm volatile("s_waitcnt vmcnt(0)" ::: "memory");
  }
  __builtin_amdgcn_s_barrier();

  for (int t = 0; t < nt; ++t) {
    const char* Ab = lds + (t & 1) * 65536 + wm * 16384;
    const char* Bb = lds + (t & 1) * 65536 + 32768 + (wn >> 1) * 16384;
    const int brow = (wn & 1) * 64;
    bf16x8 alo[4][2], ahi[4][2], bl[4][2];

    if (t + 1 < nt) { stgA0(t + 1); stgA1(t + 1); }
#pragma unroll
    for (int i = 0; i < 4; ++i)
#pragma unroll
      for (int ks = 0; ks < 2; ++ks) {
        int row = i * 16 + lr;
        alo[i][ks] = ld8(Ab + row * 128 + ((ks * 64 + lg * 16) ^ ((row & 7) << 4)));
      }
#pragma unroll
    for (int j = 0; j < 4; ++j)
#pragma unroll
      for (int ks = 0; ks < 2; ++ks) {
        int row = brow + j * 16 + lr;
        bl[j][ks] = ld8(Bb + row * 128 + ((ks * 64 + lg * 16) ^ ((row & 7) << 4)));
      }
#pragma unroll
    for (int i = 0; i < 4; ++i)
#pragma unroll
      for (int j = 0; j < 4; ++j)
#pragma unroll
        for (int ks = 0; ks < 2; ++ks)
          acc[i][j] = mfma16(alo[i][ks], bl[j][ks], acc[i][j]);
    __builtin_amdgcn_s_barrier();

    if (t + 2 < nt) { stgB0(t + 2); stgB1(t + 2); }
#pragma unroll
    for (int i = 0; i < 4; ++i)
#pragma unroll
      for (int ks = 0; ks < 2; ++ks) {
        int row = (4 + i) * 16 + lr;
        ahi[i][ks] = ld8(Ab + row * 128 + ((ks * 64 + lg * 16) ^ ((row & 7) << 4)));
      }
#pragma unroll
    for (int i = 0; i < 4; ++i)
#pragma unroll
      for (int j = 0; j < 4; ++j)
#pragma unroll
        for (int ks = 0; ks < 2; ++ks)
          acc[4 + i][j] = mfma16(ahi[i][ks], bl[j][ks], acc[4 + i][j]);
    if (t < nt - 2)
      asm volatile("s_waitcnt vmcnt(4)" ::: "memory");
    else
      asm volatile("s_waitcnt vmcnt(0)" ::: "memory");
    __builtin_amdgcn_s_barrier();
  }

  // ---- epilogue -----------------------------------------------------------
  if (EPI == 1) {
#pragma unroll
    for (int mi = 0; mi < 8; ++mi)
#pragma unroll
      for (int nj = 0; nj < 4; ++nj) {
        const int col = bxN + wn * 64 + nj * 16 + lr;
        const float bia = bias[col];
#pragma unroll
        for (int rr = 0; rr < 4; ++rr) {
          const int row = byM + wm * 128 + mi * 16 + lg * 4 + rr;
          o_f32[(size_t)row * 1024 + col] = acc[mi][nj][rr] + bia;
        }
      }
    return;
  }

  // EPI 0 / EPI 2: bounce acc through LDS (staging buffers dead).
  const int hh = bxN >> 8;  // head index (EPI 0)

  // EPI 0: early v-tile loads (32 tokens x 64 cols per wave; 64B per lane)
  us8 vreg[4];
  if (EPI == 0) {
    const u16* vrow = v_in +
        (size_t)(byM + w * 32 + (lane >> 1)) * 1024 + hh * 64 + (lane & 1) * 32;
#pragma unroll
    for (int c = 0; c < 4; ++c) vreg[c] = *(const us8*)&vrow[c * 8];
  }

  u16* cl = (u16*)lds;  // [256 rows][512 B], XOR-swizzled by (row&7)<<4
#pragma unroll
  for (int mi = 0; mi < 8; ++mi)
#pragma unroll
    for (int nj = 0; nj < 4; ++nj)
#pragma unroll
      for (int rr = 0; rr < 4; ++rr) {
        const int rl = wm * 128 + mi * 16 + lg * 4 + rr;
        const int clm = wn * 64 + nj * 16 + lr;
        float xv = acc[mi][nj][rr];
        float v = (EPI == 0) ? (xv > 0.f ? xv + 1.f : __expf(xv)) : xv;
        *(u16*)((char*)cl + ((rl * 512 + clm * 2) ^ ((rl & 7) << 4))) = f2bf(v);
      }
  __syncthreads();

  if (EPI == 2) {
#pragma unroll
    for (int it = 0; it < 16; ++it) {
      const int chunk = it * 512 + tid;
      const int r = chunk >> 5, k = chunk & 31;
      us8 val = *(us8*)((char*)cl + ((r * 512 + k * 16) ^ ((r & 7) << 4)));
      *(us8*)&o_bf16[(size_t)(byM + r) * 1024 + bxN + k * 8] = val;
    }
    return;
  }

  // ---- EPI 0: fused block attention, one 32-token block per wave ----------
  // Wave w owns bounce rows w*32..w*32+31 => contiguous 16 KB at sw.
  char* sw = (char*)lds + w * 16384;

  // S = qf @ kf^T (32x32, K=128); qf = cols 0..127, kf = cols 128..255
  f32x4 sacc[2][2];
#pragma unroll
  for (int mm = 0; mm < 2; ++mm)
#pragma unroll
    for (int nn = 0; nn < 2; ++nn) sacc[mm][nn] = (f32x4){0.f, 0.f, 0.f, 0.f};
#pragma unroll
  for (int ks = 0; ks < 4; ++ks) {
    bf16x8 aq[2], bk[2];
#pragma unroll
    for (int mm = 0; mm < 2; ++mm) {
      const int row = mm * 16 + lr;
      aq[mm] = ld8(sw + ((row * 512 + ks * 64 + lg * 16) ^ ((row & 7) << 4)));
      bk[mm] = ld8(sw + ((row * 512 + 256 + ks * 64 + lg * 16) ^ ((row & 7) << 4)));
    }
#pragma unroll
    for (int mm = 0; mm < 2; ++mm)
#pragma unroll
      for (int nn = 0; nn < 2; ++nn)
        sacc[mm][nn] = mfma16(aq[mm], bk[nn], sacc[mm][nn]);
  }

  // row sums (z denominator)
  float rs[2][4];
#pragma unroll
  for (int mm = 0; mm < 2; ++mm)
#pragma unroll
    for (int r = 0; r < 4; ++r) {
      float tv = sacc[mm][0][r] + sacc[mm][1][r];
      tv += __shfl_xor(tv, 1);
      tv += __shfl_xor(tv, 2);
      tv += __shfl_xor(tv, 4);
      tv += __shfl_xor(tv, 8);
      rs[mm][r] = tv;
    }

  // S -> bf16 into sw[0..2047] (own rows only; qf/kf reads done above)
#pragma unroll
  for (int mm = 0; mm < 2; ++mm)
#pragma unroll
    for (int nn = 0; nn < 2; ++nn)
#pragma unroll
      for (int r = 0; r < 4; ++r) {
        const int row = mm * 16 + lg * 4 + r;
        *(u16*)(sw + row * 64 + (((nn * 16 + lr) * 2) ^ ((row & 3) << 4))) =
            f2bf(sacc[mm][nn][r]);
      }

  // V regs -> padded LDS at sw+2048 (stride 144 B), then gather B-frags
#pragma unroll
  for (int c = 0; c < 4; ++c)
    *(us8*)(sw + 2048 + (lane >> 1) * 144 + (lane & 1) * 64 + c * 16) = vreg[c];
  const u16* V_l = (const u16*)(sw + 2048);  // stride 72 u16
  bf16x8 vfr[4];
#pragma unroll
  for (int nn = 0; nn < 4; ++nn) {
    us8 g;
#pragma unroll
    for (int j = 0; j < 8; ++j) g[j] = V_l[(lg * 8 + j) * 72 + nn * 16 + lr];
    vfr[nn] = __builtin_bit_cast(bf16x8, g);
  }

  // PV: out = S @ V (32x64, K=32)
  f32x4 pacc[2][4];
#pragma unroll
  for (int mm = 0; mm < 2; ++mm)
#pragma unroll
    for (int nn = 0; nn < 4; ++nn) pacc[mm][nn] = (f32x4){0.f, 0.f, 0.f, 0.f};
#pragma unroll
  for (int mm = 0; mm < 2; ++mm) {
    const int row = mm * 16 + lr;
    bf16x8 a = ld8(sw + row * 64 + ((lg * 16) ^ ((row & 3) << 4)));
#pragma unroll
    for (int nn = 0; nn < 4; ++nn) pacc[mm][nn] = mfma16(a, vfr[nn], pacc[mm][nn]);
  }

  // normalize -> bf16 out-bounce at sw+8192 ([32 rows][128 B]) -> coalesced
#pragma unroll
  for (int mm = 0; mm < 2; ++mm)
#pragma unroll
    for (int r = 0; r < 4; ++r) {
      const float z = 1.f / (rs[mm][r] + 1e-8f);
      const int row = mm * 16 + lg * 4 + r;
#pragma unroll
      for (int nn = 0; nn < 4; ++nn)
        *(u16*)(sw + 8192 + row * 128 + (nn * 16 + lr) * 2) =
            f2bf(pacc[mm][nn][r] * z);
    }
  u16* orow = o_bf16 +
      (size_t)(byM + w * 32 + (lane >> 1)) * 1024 + hh * 64 + (lane & 1) * 32;
#pragma unroll
  for (int c = 0; c < 4; ++c)
    *(us8*)&orow[c * 8] =
        *(us8*)(sw + 8192 + (lane >> 1) * 128 + (lane & 1) * 64 + c * 16);
}

// ---------------------------------------------------------------------------
extern "C" void kernel_launch(void* const* d_in, const int* in_sizes, int n_in,
                              void* d_out, int out_size, void* d_ws,
                              size_t ws_size, hipStream_t stream) {
  const float* x = (const float*)d_in[0];     // [4,4096,1024]
  const float* Wqkv = (const float*)d_in[1];  // [1024,3072]
  const float* proj = (const float*)d_in[2];  // [16,64,128]
  const float* Wout = (const float*)d_in[3];  // [1024,1024]
  const float* bout = (const float*)d_in[4];  // [1024]
  float* out = (float*)d_out;                 // [4,4096,1024] fp32

  char* ws = (char*)d_ws;
  char* doc = (char*)d_out;  // d_out as scratch: all dead before gemm3 writes

  u16* xb    = (u16*)doc;                   // 33,554,432 B  (x in bf16)
  u16* btqk  = (u16*)(doc + 33554432);      //  8,388,608 B  head-major [4096][1024]
  u16* wvT   = (u16*)(doc + 41943040);      //  2,097,152 B  [1024][1024]
  u16* vbuf  = (u16*)ws;                    // 33,554,432 B  v -> attn out (in-place)
  u16* woutT = (u16*)(ws + 33554432);       //  2,097,152 B

  cast_bf16_k<<<2048, 256, 0, stream>>>(x, xb, 4194304);
  tcastv_k<<<dim3(32, 32), 256, 0, stream>>>(Wqkv, wvT);
  wqpb_k<<<dim3(8, 16, 2), 256, 0, stream>>>(Wqkv, proj, btqk);
  tcast_k<<<dim3(32, 32), 256, 0, stream>>>(Wout, woutT, 1024, 1024);

  // v = x @ Wv  (bf16 row-major into vbuf)
  gemm8p_k<2><<<256, 512, 0, stream>>>(xb, 1024, wvT, 1024, nullptr,
                                       vbuf, nullptr, nullptr, 1024, 4);

  // qf|kf GEMM + fused block attention (overwrites vbuf in place)
  gemm8p_k<0><<<1024, 512, 0, stream>>>(xb, 1024, btqk, 1024, nullptr,
                                        vbuf, vbuf, nullptr, 1024, 16);

  // y = attn @ Wout + bout
  gemm8p_k<1><<<256, 512, 0, stream>>>(vbuf, 1024, woutT, 1024, bout,
                                       nullptr, nullptr, out, 1024, 4);
}